// Round 4
// baseline (48.275 us; speedup 1.0000x reference)
//
#include <hip/hip_runtime.h>

#define B_N   2048
#define LQ    10
#define LH    150

// One wave (64 lanes) per batch element. lane = rg*16 + c:
//   rg = lane>>4 owns pixel rows 4*rg..4*rg+3, column c = lane&15.
// Single explicit LDS arena:
//   xs   [0,648)    : padded X, ch*324 + y*18 + x
//   rp   [648,972)  : padded r
//   vp   [972,1620) : double-buffered padded v
//   effs [1620,1648): [0..17] eff_w, [18] eff_b, [19..27] fw
//   scr  [1648,1712): reduction scratch
// All conv LDS addresses are 72*rg + c + const -> 2-way bank aliasing (free).
//
// __launch_bounds__(64, 2): 2 waves/EU -> VGPR cap 256. Round-3's
// __launch_bounds__(64) let the compiler cap at 40 VGPRs and spill ~10KB/block
// to scratch (WRITE_SIZE 21MB, VALUBusy 37%). Live set here is ~180 VGPRs
// (qr[40] + wr[90] + vt[18] + addressing); 2 waves/SIMD = whole grid resident.
__global__ __launch_bounds__(64, 2) void vin_kernel(
    const float* __restrict__ X,   const float* __restrict__ S1,
    const float* __restrict__ S2,  const float* __restrict__ h_w,
    const float* __restrict__ h_b, const float* __restrict__ r_w,
    const float* __restrict__ qw,  const float* __restrict__ w,
    const float* __restrict__ fcw, float* __restrict__ out)
{
    __shared__ float smem[1712];
    float* xs   = smem;
    float* rp   = smem + 648;
    float* vp   = smem + 972;
    float* effs = smem + 1620;
    float* scr  = smem + 1648;

    const int b    = blockIdx.x;
    const int lane = threadIdx.x;
    const int rg   = lane >> 4;
    const int c    = lane & 15;

    // ---- issue X loads first (HBM latency overlaps the weight reduction) ----
    const float* Xb = X + (size_t)b * 512;
    float xreg[8];
    #pragma unroll
    for (int k = 0; k < 8; ++k) xreg[k] = Xb[lane + (k << 6)];

    // ---- zero the whole arena (conv borders must be 0) ----
    #pragma unroll
    for (int k = 0; k < 27; ++k) {
        int idx = lane + (k << 6);
        if (idx < 1712) smem[idx] = 0.f;
    }

    // ---- cooperative collapsed-weight partials (registers only here) ----
    // lanes 0..53 : eff_w[t] partial, t=lane/3, chunk=(lane%3)*50
    // lanes 54..56: eff_b partial
    float part = 0.f;
    if (lane < 54) {
        const int t  = lane / 3;
        const int h0 = (lane - t * 3) * 50;
        for (int h = h0; h < h0 + 50; ++h) part += r_w[h] * h_w[h * 18 + t];
    } else if (lane < 57) {
        const int h0 = (lane - 54) * 50;
        for (int h = h0; h < h0 + 50; ++h) part += r_w[h] * h_b[h];
    }
    __syncthreads();                      // zero-fill visible

    scr[lane] = part;
    // stage X into padded LDS
    #pragma unroll
    for (int k = 0; k < 8; ++k) {
        int e = lane + (k << 6);
        int ch = e >> 8, rem = e & 255;
        xs[ch * 324 + ((rem >> 4) + 1) * 18 + (rem & 15) + 1] = xreg[k];
    }
    // fw[t] = sum_a fc_w[a]*w[a][t]  (lanes 19..27)
    if (lane >= 19 && lane < 28) {
        const int t = lane - 19;
        float acc = 0.f;
        #pragma unroll
        for (int a = 0; a < LQ; ++a) acc += fcw[a] * w[a * 9 + t];
        effs[lane] = acc;
    }
    __syncthreads();

    if (lane < 18)       effs[lane] = scr[lane * 3] + scr[lane * 3 + 1] + scr[lane * 3 + 2];
    else if (lane == 18) effs[18]   = scr[54] + scr[55] + scr[56];
    __syncthreads();

    // ---- r = conv3x3(X, eff_w) + eff_b for this lane's 4 rows ----
    float ew[19];
    #pragma unroll
    for (int t = 0; t < 19; ++t) ew[t] = effs[t];

    float xt[2][6][3];
    #pragma unroll
    for (int ch = 0; ch < 2; ++ch)
        #pragma unroll
        for (int dy = 0; dy < 6; ++dy)
            #pragma unroll
            for (int dx = 0; dx < 3; ++dx)
                xt[ch][dy][dx] = xs[ch * 324 + ((rg << 2) + dy) * 18 + c + dx];

    #pragma unroll
    for (int k = 0; k < 4; ++k) {
        float acc = ew[18];
        #pragma unroll
        for (int ch = 0; ch < 2; ++ch)
            #pragma unroll
            for (int ky = 0; ky < 3; ++ky)
                #pragma unroll
                for (int kx = 0; kx < 3; ++kx)
                    acc += xt[ch][k + ky][kx] * ew[ch * 9 + ky * 3 + kx];
        rp[((rg << 2) + k + 1) * 18 + c + 1] = acc;
    }
    __syncthreads();

    // ---- qr[k][a] = conv3x3(r, q_w)[a]  (iteration-invariant half) ----
    float rt[6][3];
    #pragma unroll
    for (int dy = 0; dy < 6; ++dy)
        #pragma unroll
        for (int dx = 0; dx < 3; ++dx)
            rt[dy][dx] = rp[((rg << 2) + dy) * 18 + c + dx];

    float qr[4][LQ];
    #pragma unroll
    for (int k = 0; k < 4; ++k)
        #pragma unroll
        for (int a = 0; a < LQ; ++a) {
            float acc = 0.f;
            #pragma unroll
            for (int ky = 0; ky < 3; ++ky)
                #pragma unroll
                for (int kx = 0; kx < 3; ++kx)
                    acc += rt[k + ky][kx] * qw[a * 9 + ky * 3 + kx];
            qr[k][a] = acc;
        }

    // ---- hoist VI weights into registers ----
    float wr[LQ * 9];
    #pragma unroll
    for (int t = 0; t < LQ * 9; ++t) wr[t] = w[t];

    // ---- v0 = max_a qr ----
    #pragma unroll
    for (int k = 0; k < 4; ++k) {
        float m = qr[k][0];
        #pragma unroll
        for (int a = 1; a < LQ; ++a) m = fmaxf(m, qr[k][a]);
        vp[0 * 324 + ((rg << 2) + k + 1) * 18 + c + 1] = m;
    }
    __syncthreads();

    // ---- 19 value-iteration sweeps (single-wave barriers ~ free) ----
#define VSTEP(SRC, DST)                                                       \
    {                                                                         \
        float vt[6][3];                                                       \
        _Pragma("unroll")                                                     \
        for (int dy = 0; dy < 6; ++dy)                                        \
            _Pragma("unroll")                                                 \
            for (int dx = 0; dx < 3; ++dx)                                    \
                vt[dy][dx] = vp[(SRC) * 324 + ((rg << 2) + dy) * 18 + c + dx];\
        _Pragma("unroll")                                                     \
        for (int k = 0; k < 4; ++k) {                                         \
            float m;                                                          \
            _Pragma("unroll")                                                 \
            for (int a = 0; a < LQ; ++a) {                                    \
                float acc = qr[k][a];                                         \
                _Pragma("unroll")                                             \
                for (int ky = 0; ky < 3; ++ky)                                \
                    _Pragma("unroll")                                         \
                    for (int kx = 0; kx < 3; ++kx)                            \
                        acc += vt[k + ky][kx] * wr[a * 9 + ky * 3 + kx];      \
                m = (a == 0) ? acc : fmaxf(m, acc);                           \
            }                                                                 \
            vp[(DST) * 324 + ((rg << 2) + k + 1) * 18 + c + 1] = m;           \
        }                                                                     \
        __syncthreads();                                                      \
    }

    #pragma unroll 1
    for (int it = 0; it < 9; ++it) {
        VSTEP(0, 1)
        VSTEP(1, 0)
    }
    VSTEP(0, 1)   // step 19; final v lives in vp[1]

    // ---- final conv + gather + fc at (s1, s2) only ----
    const float s1f = S1[b], s2f = S2[b];
    int s1 = (int)floorf((s1f + 50.0f) / 6.25f);
    int s2 = (int)floorf((s2f + 50.0f) / 6.25f);
    s1 = min(max(s1, 0), 15);
    s2 = min(max(s2, 0), 15);

    if (rg == (s1 >> 2) && c == s2) {
        const int k = s1 & 3;
        float logit = 0.f;
        #pragma unroll
        for (int a = 0; a < LQ; ++a) logit += fcw[a] * qr[k][a];
        #pragma unroll
        for (int ky = 0; ky < 3; ++ky)
            #pragma unroll
            for (int kx = 0; kx < 3; ++kx)
                logit += vp[324 + (s1 + ky) * 18 + s2 + kx] * effs[19 + ky * 3 + kx];
        out[b]       = logit;   // logits
        out[B_N + b] = 1.0f;    // softmax over length-1 axis == 1
    }
#undef VSTEP
}

extern "C" void kernel_launch(void* const* d_in, const int* in_sizes, int n_in,
                              void* d_out, int out_size, void* d_ws, size_t ws_size,
                              hipStream_t stream) {
    const float* X    = (const float*)d_in[0];
    const float* S1   = (const float*)d_in[1];
    const float* S2   = (const float*)d_in[2];
    const float* h_w  = (const float*)d_in[3];
    const float* h_b  = (const float*)d_in[4];
    const float* r_w  = (const float*)d_in[5];
    const float* q_w  = (const float*)d_in[6];
    const float* w    = (const float*)d_in[7];
    const float* fc_w = (const float*)d_in[8];
    float*       out  = (float*)d_out;

    vin_kernel<<<B_N, 64, 0, stream>>>(X, S1, S2, h_w, h_b, r_w, q_w, w, fc_w, out);
}

// Round 5
// 45.498 us; speedup vs baseline: 1.0610x; 1.0610x over previous
//
#include <hip/hip_runtime.h>

#define B_N   2048
#define LQ    10
#define LH    150

// One wave (64 lanes) per batch element. lane = rg*16 + c:
//   rg = lane>>4 owns pixel rows 4*rg..4*rg+3, column c = lane&15.
// Single explicit LDS arena:
//   xs   [0,648)    : padded X, ch*324 + y*18 + x
//   rp   [648,972)  : padded r
//   vp   [972,1620) : double-buffered padded v
//   effs [1620,1648): [0..17] eff_w, [18] eff_b, [19..27] fw
//   scr  [1648,1712): reduction scratch
// All conv LDS addresses are 72*rg + c + const -> 2-way bank aliasing (free).
//
// CRITICAL (round-4 lesson): no runtime indexing into register arrays.
// qr[k][a] with runtime k forced the whole qr array to scratch
// (WRITE_SIZE 20.6MB = 10KB/block = qr's exact footprint, VALUBusy 40%).
// Epilogue now uses static-index dots + a scalar ternary select.
__global__ __launch_bounds__(64, 2) void vin_kernel(
    const float* __restrict__ X,   const float* __restrict__ S1,
    const float* __restrict__ S2,  const float* __restrict__ h_w,
    const float* __restrict__ h_b, const float* __restrict__ r_w,
    const float* __restrict__ qw,  const float* __restrict__ w,
    const float* __restrict__ fcw, float* __restrict__ out)
{
    __shared__ float smem[1712];
    float* xs   = smem;
    float* rp   = smem + 648;
    float* vp   = smem + 972;
    float* effs = smem + 1620;
    float* scr  = smem + 1648;

    const int b    = blockIdx.x;
    const int lane = threadIdx.x;
    const int rg   = lane >> 4;
    const int c    = lane & 15;

    // ---- issue X loads first (HBM latency overlaps the weight reduction) ----
    const float* Xb = X + (size_t)b * 512;
    float xreg[8];
    #pragma unroll
    for (int k = 0; k < 8; ++k) xreg[k] = Xb[lane + (k << 6)];

    // ---- zero the whole arena (conv borders must be 0) ----
    #pragma unroll
    for (int k = 0; k < 27; ++k) {
        int idx = lane + (k << 6);
        if (idx < 1712) smem[idx] = 0.f;
    }

    // ---- cooperative collapsed-weight partials (registers only here) ----
    // lanes 0..53 : eff_w[t] partial, t=lane/3, chunk=(lane%3)*50
    // lanes 54..56: eff_b partial
    float part = 0.f;
    if (lane < 54) {
        const int t  = lane / 3;
        const int h0 = (lane - t * 3) * 50;
        for (int h = h0; h < h0 + 50; ++h) part += r_w[h] * h_w[h * 18 + t];
    } else if (lane < 57) {
        const int h0 = (lane - 54) * 50;
        for (int h = h0; h < h0 + 50; ++h) part += r_w[h] * h_b[h];
    }
    __syncthreads();                      // zero-fill visible

    scr[lane] = part;
    // stage X into padded LDS
    #pragma unroll
    for (int k = 0; k < 8; ++k) {
        int e = lane + (k << 6);
        int ch = e >> 8, rem = e & 255;
        xs[ch * 324 + ((rem >> 4) + 1) * 18 + (rem & 15) + 1] = xreg[k];
    }
    // fw[t] = sum_a fc_w[a]*w[a][t]  (lanes 19..27)
    if (lane >= 19 && lane < 28) {
        const int t = lane - 19;
        float acc = 0.f;
        #pragma unroll
        for (int a = 0; a < LQ; ++a) acc += fcw[a] * w[a * 9 + t];
        effs[lane] = acc;
    }
    __syncthreads();

    if (lane < 18)       effs[lane] = scr[lane * 3] + scr[lane * 3 + 1] + scr[lane * 3 + 2];
    else if (lane == 18) effs[18]   = scr[54] + scr[55] + scr[56];
    __syncthreads();

    // ---- r = conv3x3(X, eff_w) + eff_b for this lane's 4 rows ----
    float ew[19];
    #pragma unroll
    for (int t = 0; t < 19; ++t) ew[t] = effs[t];

    float xt[2][6][3];
    #pragma unroll
    for (int ch = 0; ch < 2; ++ch)
        #pragma unroll
        for (int dy = 0; dy < 6; ++dy)
            #pragma unroll
            for (int dx = 0; dx < 3; ++dx)
                xt[ch][dy][dx] = xs[ch * 324 + ((rg << 2) + dy) * 18 + c + dx];

    #pragma unroll
    for (int k = 0; k < 4; ++k) {
        float acc = ew[18];
        #pragma unroll
        for (int ch = 0; ch < 2; ++ch)
            #pragma unroll
            for (int ky = 0; ky < 3; ++ky)
                #pragma unroll
                for (int kx = 0; kx < 3; ++kx)
                    acc += xt[ch][k + ky][kx] * ew[ch * 9 + ky * 3 + kx];
        rp[((rg << 2) + k + 1) * 18 + c + 1] = acc;
    }
    __syncthreads();

    // ---- qr[k][a] = conv3x3(r, q_w)[a]  (iteration-invariant half) ----
    float rt[6][3];
    #pragma unroll
    for (int dy = 0; dy < 6; ++dy)
        #pragma unroll
        for (int dx = 0; dx < 3; ++dx)
            rt[dy][dx] = rp[((rg << 2) + dy) * 18 + c + dx];

    float qr[4][LQ];
    #pragma unroll
    for (int k = 0; k < 4; ++k)
        #pragma unroll
        for (int a = 0; a < LQ; ++a) {
            float acc = 0.f;
            #pragma unroll
            for (int ky = 0; ky < 3; ++ky)
                #pragma unroll
                for (int kx = 0; kx < 3; ++kx)
                    acc += rt[k + ky][kx] * qw[a * 9 + ky * 3 + kx];
            qr[k][a] = acc;
        }

    // ---- hoist VI weights into registers ----
    float wr[LQ * 9];
    #pragma unroll
    for (int t = 0; t < LQ * 9; ++t) wr[t] = w[t];

    // ---- v0 = max_a qr ----
    #pragma unroll
    for (int k = 0; k < 4; ++k) {
        float m = qr[k][0];
        #pragma unroll
        for (int a = 1; a < LQ; ++a) m = fmaxf(m, qr[k][a]);
        vp[0 * 324 + ((rg << 2) + k + 1) * 18 + c + 1] = m;
    }
    __syncthreads();

    // ---- 19 value-iteration sweeps (single-wave barriers ~ free) ----
#define VSTEP(SRC, DST)                                                       \
    {                                                                         \
        float vt[6][3];                                                       \
        _Pragma("unroll")                                                     \
        for (int dy = 0; dy < 6; ++dy)                                        \
            _Pragma("unroll")                                                 \
            for (int dx = 0; dx < 3; ++dx)                                    \
                vt[dy][dx] = vp[(SRC) * 324 + ((rg << 2) + dy) * 18 + c + dx];\
        _Pragma("unroll")                                                     \
        for (int k = 0; k < 4; ++k) {                                         \
            float m;                                                          \
            _Pragma("unroll")                                                 \
            for (int a = 0; a < LQ; ++a) {                                    \
                float acc = qr[k][a];                                         \
                _Pragma("unroll")                                             \
                for (int ky = 0; ky < 3; ++ky)                                \
                    _Pragma("unroll")                                         \
                    for (int kx = 0; kx < 3; ++kx)                            \
                        acc += vt[k + ky][kx] * wr[a * 9 + ky * 3 + kx];      \
                m = (a == 0) ? acc : fmaxf(m, acc);                           \
            }                                                                 \
            vp[(DST) * 324 + ((rg << 2) + k + 1) * 18 + c + 1] = m;           \
        }                                                                     \
        __syncthreads();                                                      \
    }

    #pragma unroll 1
    for (int it = 0; it < 9; ++it) {
        VSTEP(0, 1)
        VSTEP(1, 0)
    }
    VSTEP(0, 1)   // step 19; final v lives in vp[1]

    // ---- final conv + gather + fc at (s1, s2) only ----
    const float s1f = S1[b], s2f = S2[b];
    int s1 = (int)floorf((s1f + 50.0f) / 6.25f);
    int s2 = (int)floorf((s2f + 50.0f) / 6.25f);
    s1 = min(max(s1, 0), 15);
    s2 = min(max(s2, 0), 15);

    if (rg == (s1 >> 2) && c == s2) {
        // static-index dot products; runtime select on NAMED SCALARS only
        float d0 = 0.f, d1 = 0.f, d2 = 0.f, d3 = 0.f;
        #pragma unroll
        for (int a = 0; a < LQ; ++a) {
            d0 += fcw[a] * qr[0][a];
            d1 += fcw[a] * qr[1][a];
            d2 += fcw[a] * qr[2][a];
            d3 += fcw[a] * qr[3][a];
        }
        const int kk = s1 & 3;
        float logit = (kk == 0) ? d0 : (kk == 1) ? d1 : (kk == 2) ? d2 : d3;
        #pragma unroll
        for (int ky = 0; ky < 3; ++ky)
            #pragma unroll
            for (int kx = 0; kx < 3; ++kx)
                logit += vp[324 + (s1 + ky) * 18 + s2 + kx] * effs[19 + ky * 3 + kx];
        out[b]       = logit;   // logits
        out[B_N + b] = 1.0f;    // softmax over length-1 axis == 1
    }
#undef VSTEP
}

extern "C" void kernel_launch(void* const* d_in, const int* in_sizes, int n_in,
                              void* d_out, int out_size, void* d_ws, size_t ws_size,
                              hipStream_t stream) {
    const float* X    = (const float*)d_in[0];
    const float* S1   = (const float*)d_in[1];
    const float* S2   = (const float*)d_in[2];
    const float* h_w  = (const float*)d_in[3];
    const float* h_b  = (const float*)d_in[4];
    const float* r_w  = (const float*)d_in[5];
    const float* q_w  = (const float*)d_in[6];
    const float* w    = (const float*)d_in[7];
    const float* fc_w = (const float*)d_in[8];
    float*       out  = (float*)d_out;

    vin_kernel<<<B_N, 64, 0, stream>>>(X, S1, S2, h_w, h_b, r_w, q_w, w, fc_w, out);
}